// Round 1
// baseline (151.748 us; speedup 1.0000x reference)
//
#include <hip/hip_runtime.h>

namespace {
constexpr int AH = 9, AW = 9, NS = AH * AW;   // 81 samples per ROI
constexpr int C = 256, H = 64, W = 64;
constexpr float SCALE = 0.0625f;
constexpr int ELEMS = C * NS;                 // 20736 outputs per ROI
}

__global__ __launch_bounds__(256, 8)
void rod_align_kernel(const float* __restrict__ feat,
                      const float* __restrict__ rois,
                      float* __restrict__ out)
{
    __shared__ float4 s_w[NS];   // premultiplied bilinear weights (0 if invalid)
    __shared__ int    s_off[NS]; // y0*W + x0

    const int r = blockIdx.x;
    const int t = threadIdx.x;

    // ---- per-ROI geometry (threads 0..80) ----
    const float* roi = rois + r * 5;
    const int   b  = (int)roi[0];
    const float x1 = roi[1] * SCALE;
    const float y1 = roi[2] * SCALE;
    const float x2 = roi[3] * SCALE;
    const float y2 = roi[4] * SCALE;
    const float bin_h = (y2 - y1) * 0.125f;   // /(AH-1), exact pow2
    const float bin_w = (x2 - x1) * 0.125f;

    if (t < NS) {
        const int i = t / AW;
        const int j = t - i * AW;
        const float Y = y1 + (float)i * bin_h;
        const float X = x1 + (float)j * bin_w;
        const bool valid = (Y >= 0.f) && (Y < (float)H) &&
                           (X >= 0.f) && (X < (float)W);
        const float fy = fminf(fmaxf(floorf(Y), 0.f), (float)(H - 2));
        const float fx = fminf(fmaxf(floorf(X), 0.f), (float)(W - 2));
        const float ly = Y - fy, lx = X - fx;   // may exceed 1 at border, matches ref
        const float hy = 1.f - ly, hx = 1.f - lx;
        const float v = valid ? 1.f : 0.f;
        s_off[t] = (int)fy * W + (int)fx;
        s_w[t] = make_float4(hy * hx * v, hy * lx * v, ly * hx * v, ly * lx * v);
    }
    __syncthreads();

    const float* __restrict__ fb = feat + (size_t)b * (C * H * W);
    float* __restrict__ ob = out + (size_t)r * ELEMS;

    // flat element index e = t + 256*it over c*81+s; track (c,s) incrementally
    int c = t / NS;          // 0..3
    int s = t - c * NS;
    #pragma unroll 3
    for (int it = 0; it < NS; ++it) {
        const int off = (c << 12) + s_off[s];   // c*H*W + y0*W + x0
        const float4 w = s_w[s];                // one ds_read_b128
        const float f00 = fb[off];
        const float f01 = fb[off + 1];
        const float f10 = fb[off + W];
        const float f11 = fb[off + W + 1];
        ob[t + (it << 8)] = f00 * w.x + f01 * w.y + f10 * w.z + f11 * w.w;
        c += 3; s += 13;                        // e += 256 (256 = 3*81 + 13)
        if (s >= NS) { s -= NS; ++c; }
    }
}

extern "C" void kernel_launch(void* const* d_in, const int* in_sizes, int n_in,
                              void* d_out, int out_size, void* d_ws, size_t ws_size,
                              hipStream_t stream) {
    const float* feat = (const float*)d_in[0];
    const float* rois = (const float*)d_in[1];
    float* outp = (float*)d_out;
    const int R = in_sizes[1] / 5;   // 2048
    rod_align_kernel<<<R, 256, 0, stream>>>(feat, rois, outp);
}

// Round 2
// 65.980 us; speedup vs baseline: 2.2999x; 2.2999x over previous
//
#include <hip/hip_runtime.h>

namespace {
constexpr int AH = 9, AW = 9, NS = AH * AW;   // 81 samples per ROI
constexpr int C = 256, H = 64, W = 64;
constexpr float SCALE = 0.0625f;
constexpr int ELEMS = C * NS;                 // 20736 outputs per ROI
constexpr int CH = 64;                        // channels per chunk (main kernel)
constexpr size_t FEAT_ELEMS = (size_t)4 * C * H * W;   // 4.19M floats = 16 MB
}

// ---------- pass 1: NCHW -> NHWC transpose into workspace ----------
// per batch: A[c][p] (256 x 4096) -> T[p][c] (4096 x 256), p = h*64+w
__global__ __launch_bounds__(256)
void nchw_to_nhwc_kernel(const float* __restrict__ in, float* __restrict__ out)
{
    __shared__ float tile[32][33];
    const int b  = blockIdx.z;
    const int p0 = blockIdx.x * 32;
    const int c0 = blockIdx.y * 32;
    const float* src = in  + (size_t)b * C * (H * W);
    float*       dst = out + (size_t)b * (H * W) * C;
    const int tx = threadIdx.x;   // 0..31
    const int ty = threadIdx.y;   // 0..7
    #pragma unroll
    for (int k = 0; k < 4; ++k)
        tile[ty + 8 * k][tx] = src[(size_t)(c0 + ty + 8 * k) * (H * W) + p0 + tx];
    __syncthreads();
    #pragma unroll
    for (int k = 0; k < 4; ++k)
        dst[(size_t)(p0 + ty + 8 * k) * C + c0 + tx] = tile[tx][ty + 8 * k];
}

// ---------- pass 2: ROI align from NHWC ----------
// grid = 2*R blocks; block handles one ROI x two 64-channel chunks.
__global__ __launch_bounds__(256)
void rod_align_nhwc_kernel(const float* __restrict__ nhwc,
                           const float* __restrict__ rois,
                           float* __restrict__ out)
{
    __shared__ float4 s_w[NS];
    __shared__ int    s_off[NS];            // ((y0*W + x0) * C)
    __shared__ float  s_buf[NS][CH + 1];    // padded: conflict-free both ways

    const int r    = blockIdx.x >> 1;
    const int half = blockIdx.x & 1;
    const int t    = threadIdx.x;
    const int wave = t >> 6;
    const int lane = t & 63;

    const float* roi = rois + r * 5;
    const int   b  = (int)roi[0];
    const float x1 = roi[1] * SCALE;
    const float y1 = roi[2] * SCALE;
    const float x2 = roi[3] * SCALE;
    const float y2 = roi[4] * SCALE;
    const float bin_h = (y2 - y1) * 0.125f;
    const float bin_w = (x2 - x1) * 0.125f;

    if (t < NS) {
        const int i = t / AW;
        const int j = t - i * AW;
        const float Y = y1 + (float)i * bin_h;
        const float X = x1 + (float)j * bin_w;
        const bool valid = (Y >= 0.f) && (Y < (float)H) &&
                           (X >= 0.f) && (X < (float)W);
        const float fy = fminf(fmaxf(floorf(Y), 0.f), (float)(H - 2));
        const float fx = fminf(fmaxf(floorf(X), 0.f), (float)(W - 2));
        const float ly = Y - fy, lx = X - fx;
        const float hy = 1.f - ly, hx = 1.f - lx;
        const float v = valid ? 1.f : 0.f;
        s_off[t] = ((int)fy * W + (int)fx) * C;
        s_w[t] = make_float4(hy * hx * v, hy * lx * v, ly * hx * v, ly * lx * v);
    }
    __syncthreads();

    const float* __restrict__ fb = nhwc + (size_t)b * (H * W * C);
    float* __restrict__ ob = out + (size_t)r * ELEMS;

    for (int ci = 0; ci < 2; ++ci) {
        const int c0 = (half * 2 + ci) * CH;
        const float* __restrict__ fc = fb + c0 + lane;
        // compute: wave w covers samples s = w, w+4, ... (reads coalesced in c)
        for (int s = wave; s < NS; s += 4) {
            const int off = s_off[s];
            const float4 w4 = s_w[s];
            const float v = fc[off]             * w4.x
                          + fc[off + C]         * w4.y
                          + fc[off + W * C]     * w4.z
                          + fc[off + W * C + C] * w4.w;
            s_buf[s][lane] = v;
        }
        __syncthreads();
        // write: contiguous 5184-float slab  out[r, c0+cc, s], f = cc*81 + s
        float* __restrict__ oc = ob + c0 * NS;
        for (int f = t; f < CH * NS; f += 256) {
            const int cc = f / NS;
            const int ss = f - cc * NS;
            oc[f] = s_buf[ss][cc];
        }
        __syncthreads();
    }
}

// ---------- fallback (round-1 kernel) if workspace is too small ----------
__global__ __launch_bounds__(256, 8)
void rod_align_nchw_kernel(const float* __restrict__ feat,
                           const float* __restrict__ rois,
                           float* __restrict__ out)
{
    __shared__ float4 s_w[NS];
    __shared__ int    s_off[NS];

    const int r = blockIdx.x;
    const int t = threadIdx.x;

    const float* roi = rois + r * 5;
    const int   b  = (int)roi[0];
    const float x1 = roi[1] * SCALE;
    const float y1 = roi[2] * SCALE;
    const float x2 = roi[3] * SCALE;
    const float y2 = roi[4] * SCALE;
    const float bin_h = (y2 - y1) * 0.125f;
    const float bin_w = (x2 - x1) * 0.125f;

    if (t < NS) {
        const int i = t / AW;
        const int j = t - i * AW;
        const float Y = y1 + (float)i * bin_h;
        const float X = x1 + (float)j * bin_w;
        const bool valid = (Y >= 0.f) && (Y < (float)H) &&
                           (X >= 0.f) && (X < (float)W);
        const float fy = fminf(fmaxf(floorf(Y), 0.f), (float)(H - 2));
        const float fx = fminf(fmaxf(floorf(X), 0.f), (float)(W - 2));
        const float ly = Y - fy, lx = X - fx;
        const float hy = 1.f - ly, hx = 1.f - lx;
        const float v = valid ? 1.f : 0.f;
        s_off[t] = (int)fy * W + (int)fx;
        s_w[t] = make_float4(hy * hx * v, hy * lx * v, ly * hx * v, ly * lx * v);
    }
    __syncthreads();

    const float* __restrict__ fb = feat + (size_t)b * (C * H * W);
    float* __restrict__ ob = out + (size_t)r * ELEMS;

    int c = t / NS;
    int s = t - c * NS;
    #pragma unroll 3
    for (int it = 0; it < NS; ++it) {
        const int off = (c << 12) + s_off[s];
        const float4 w = s_w[s];
        const float f00 = fb[off];
        const float f01 = fb[off + 1];
        const float f10 = fb[off + W];
        const float f11 = fb[off + W + 1];
        ob[t + (it << 8)] = f00 * w.x + f01 * w.y + f10 * w.z + f11 * w.w;
        c += 3; s += 13;
        if (s >= NS) { s -= NS; ++c; }
    }
}

extern "C" void kernel_launch(void* const* d_in, const int* in_sizes, int n_in,
                              void* d_out, int out_size, void* d_ws, size_t ws_size,
                              hipStream_t stream) {
    const float* feat = (const float*)d_in[0];
    const float* rois = (const float*)d_in[1];
    float* outp = (float*)d_out;
    const int R = in_sizes[1] / 5;   // 2048

    if (ws_size >= FEAT_ELEMS * sizeof(float)) {
        float* nhwc = (float*)d_ws;
        dim3 tgrid(H * W / 32, C / 32, 4);
        dim3 tblk(32, 8);
        nchw_to_nhwc_kernel<<<tgrid, tblk, 0, stream>>>(feat, nhwc);
        rod_align_nhwc_kernel<<<2 * R, 256, 0, stream>>>(nhwc, rois, outp);
    } else {
        rod_align_nchw_kernel<<<R, 256, 0, stream>>>(feat, rois, outp);
    }
}